// Round 17
// baseline (1100.762 us; speedup 1.0000x reference)
//
#include <hip/hip_runtime.h>
#include <hip/hip_bf16.h>
#include <math.h>

// Problem constants
#define B_   32
#define S_   512
#define V_   30000
#define E_   300
#define H_   200
#define NH_  4
#define ENC_ 400
#define G4_  800     // 4*H
#define NEGV  (-1e9f)
#define SCALE_ 1000.0f

typedef _Float16 half2v __attribute__((ext_vector_type(2)));
typedef _Float16 f16x8  __attribute__((ext_vector_type(8)));
typedef float    f32x4  __attribute__((ext_vector_type(4)));

#if defined(__has_builtin)
#if __has_builtin(__builtin_amdgcn_fdot2)
#define FDOT2(a,b,c) __builtin_amdgcn_fdot2((a),(b),(c),false)
#endif
#endif
#ifndef FDOT2
#define FDOT2(a,b,c) fmaf((float)(a)[1],(float)(b)[1], fmaf((float)(a)[0],(float)(b)[0],(c)))
#endif

// ---- workspace layout (float offsets) ----
#define OF_WKQ   320448ull     // wkq [400][4]
#define OF_THETA 322048ull     // theta [B][4][512]
#define OF_LEN   504320ull     // lengths (int) [32]
#define OF_XWF   504384ull     // xW forward  [B*S][800]
#define OF_XWB   13611584ull   // xW backward [B*S][800]
#define OF_HF    26718784ull   // h_f [B*S][200]
#define OF_HB    29995584ull   // h_b [B*S][200]

// -------- k_prep: lengths (blocks 0..31) + wkq with in-block qvec (32..38) --------
__global__ __launch_bounds__(256) void k_prep(
    const void* __restrict__ mask, int* __restrict__ lengths,
    const float* __restrict__ qs, const float* __restrict__ Wq,
    const float* __restrict__ Wk, float* __restrict__ wkq)
{
  const int blk = blockIdx.x, t = threadIdx.x;
  __shared__ float shb[800];
  if (blk < 32) {
    int* red = (int*)shb;
    const unsigned char* mb = (const unsigned char*)mask;
    int mode;
    if (mb[1] != 0) mode = 0;
    else if (((const int*)mask)[1] != 0) mode = 1;
    else mode = 2;
    int cnt = 0;
    for (int s = t; s < S_; s += 256) {
      int v;
      if (mode == 0)      v = mb[blk*S_ + s] ? 1 : 0;
      else if (mode == 1) v = ((const int*)mask)[blk*S_ + s] ? 1 : 0;
      else                v = ((const long long*)mask)[blk*S_ + s] ? 1 : 0;
      cnt += v;
    }
    red[t] = cnt;
    __syncthreads();
    for (int sft = 128; sft; sft >>= 1) {
      if (t < sft) red[t] += red[t+sft];
      __syncthreads();
    }
    if (t == 0) lengths[blk] = red[0];
  } else {
    float* qsl = shb;              // [400]
    float* qv  = shb + 400;        // [400]
    if (t < ENC_) qsl[t] = qs[t];
    if (t + 256 < ENC_) qsl[t+256] = qs[t+256];
    __syncthreads();
    {
      float acc = 0.f;
      for (int i = 0; i < ENC_; ++i) acc += qsl[i] * Wq[(size_t)i*ENC_ + t];
      qv[t] = acc;
      if (t + 256 < ENC_) {
        float acc2 = 0.f;
        for (int i = 0; i < ENC_; ++i) acc2 += qsl[i] * Wq[(size_t)i*ENC_ + t + 256];
        qv[t+256] = acc2;
      }
    }
    __syncthreads();
    const int e = (blk - 32)*64 + (t >> 2);
    const int head = t & 3;
    if (e < ENC_) {
      float acc = 0.f;
      const float* row = Wk + (size_t)e*ENC_ + head*100;
      const float* qvh = qv + head*100;
      for (int d = 0; d < 100; ++d) acc += row[d]*qvh[d];
      wkq[e*4 + head] = acc;
    }
  }
}

// -------- input projections via fp16 MFMA (builtins only; passing) --------
__global__ __launch_bounds__(256) void k_gemm_mfma(
    const int* __restrict__ x, const float* __restrict__ emb,
    const float* __restrict__ wf, const float* __restrict__ wb,
    const float* __restrict__ bf, const float* __restrict__ bb,
    float* __restrict__ xWf, float* __restrict__ xWb)
{
  __shared__ int xid[128];
  __shared__ __align__(16) _Float16 sA[128][40];
  __shared__ __align__(16) _Float16 sB[64][40];
  const int t = threadIdx.x;
  const int row0 = blockIdx.x * 128;
  const int col0 = blockIdx.y * 64;
  if (t < 128) xid[t] = x[row0 + t];
  const int w = t >> 6, lane = t & 63;
  const int wr = w >> 1, wc = w & 1;
  f32x4 acc[4][2] = {};
  const int ar = t >> 1, ah = t & 1;
  const int bc = t >> 2, bq = t & 3;
  const int colg = col0 + bc;
  const float* wsrc = (colg < 800) ? (wf + (size_t)colg*300)
                                   : (wb + (size_t)(colg-800)*300);
  __syncthreads();
  const float* asrc = emb + (size_t)xid[ar]*300;
  for (int kc = 0; kc < 10; ++kc) {
    const int k0 = kc*32;
    {
      const int kb = k0 + ah*16;
      _Float16 tmp[16];
      if (kb + 15 < 300) {
        #pragma unroll
        for (int q = 0; q < 4; ++q) {
          float4 a = *(const float4*)(asrc + kb + 4*q);
          tmp[4*q]  =(_Float16)a.x; tmp[4*q+1]=(_Float16)a.y;
          tmp[4*q+2]=(_Float16)a.z; tmp[4*q+3]=(_Float16)a.w;
        }
      } else {
        #pragma unroll
        for (int i = 0; i < 16; ++i)
          tmp[i] = (_Float16)((kb+i < 300) ? asrc[kb+i] : 0.f);
      }
      *(f16x8*)&sA[ar][ah*16]   = *(f16x8*)&tmp[0];
      *(f16x8*)&sA[ar][ah*16+8] = *(f16x8*)&tmp[8];
    }
    {
      const int kb = k0 + bq*8;
      _Float16 tmp[8];
      if (kb + 7 < 300) {
        #pragma unroll
        for (int q = 0; q < 2; ++q) {
          float4 a = *(const float4*)(wsrc + kb + 4*q);
          tmp[4*q]  =(_Float16)a.x; tmp[4*q+1]=(_Float16)a.y;
          tmp[4*q+2]=(_Float16)a.z; tmp[4*q+3]=(_Float16)a.w;
        }
      } else {
        #pragma unroll
        for (int i = 0; i < 8; ++i)
          tmp[i] = (_Float16)((kb+i < 300) ? wsrc[kb+i] : 0.f);
      }
      *(f16x8*)&sB[bc][bq*8] = *(f16x8*)&tmp[0];
    }
    __syncthreads();
    const int fr = lane & 15, kg = lane >> 4;
    f16x8 b0 = *(const f16x8*)&sB[wc*32 + fr][kg*8];
    f16x8 b1 = *(const f16x8*)&sB[wc*32 + 16 + fr][kg*8];
    #pragma unroll
    for (int m = 0; m < 4; ++m) {
      f16x8 afrag = *(const f16x8*)&sA[wr*64 + m*16 + fr][kg*8];
      acc[m][0] = __builtin_amdgcn_mfma_f32_16x16x32_f16(afrag, b0, acc[m][0], 0,0,0);
      acc[m][1] = __builtin_amdgcn_mfma_f32_16x16x32_f16(afrag, b1, acc[m][1], 0,0,0);
    }
    __syncthreads();
  }
  const int crb = (lane >> 4) * 4, ccol = lane & 15;
  #pragma unroll
  for (int n = 0; n < 2; ++n) {
    int colg2 = col0 + wc*32 + n*16 + ccol;
    bool isF = colg2 < 800;
    int colo = isF ? colg2 : colg2 - 800;
    float bias = isF ? bf[colo] : bb[colo];
    float* dst = isF ? xWf : xWb;
    #pragma unroll
    for (int m = 0; m < 4; ++m) {
      int row = row0 + wr*64 + m*16 + crb;
      #pragma unroll
      for (int r = 0; r < 4; ++r)
        dst[(size_t)(row+r)*800 + colo] = acc[m][n][r] + bias;
    }
  }
}

// -------- fallback LSTM — round-3 k_lstm_ws verbatim (measured 645 us) --------
__global__ __launch_bounds__(512, 2) void k_lstm_ws(
    const float* __restrict__ xWf, const float* __restrict__ xWb,
    const float* __restrict__ whhf, const float* __restrict__ whhb,
    const int* __restrict__ lengths,
    float* __restrict__ h_f, float* __restrict__ h_b)
{
  const int bid = blockIdx.x;
  const int dir = bid >> 5, b = bid & 31;
  const float* __restrict__ xW  = dir ? xWb : xWf;
  const float* __restrict__ whh = dir ? whhb : whhf;
  float* __restrict__ hout      = dir ? h_b : h_f;
  const int len = lengths[b];
  const int t = threadIdx.x;

  __shared__ __align__(16) _Float16 hb[256];
  __shared__ float sums[1024];

  half2v w0[100], w1[100];
  {
    const float* r0p = whh + (size_t)t*H_;
    #pragma unroll
    for (int j = 0; j < 50; ++j) {
      float4 a = *(const float4*)(r0p + 4*j);
      w0[2*j]   = half2v{(_Float16)a.x, (_Float16)a.y};
      w0[2*j+1] = half2v{(_Float16)a.z, (_Float16)a.w};
    }
    if (t < 288) {
      const float* r1p = whh + (size_t)(512+t)*H_;
      #pragma unroll
      for (int j = 0; j < 50; ++j) {
        float4 a = *(const float4*)(r1p + 4*j);
        w1[2*j]   = half2v{(_Float16)a.x, (_Float16)a.y};
        w1[2*j+1] = half2v{(_Float16)a.z, (_Float16)a.w};
      }
    } else {
      #pragma unroll
      for (int j = 0; j < 100; ++j) w1[j] = half2v{(_Float16)0.f, (_Float16)0.f};
    }
  }

  if (t < 256) hb[t] = (_Float16)0.f;
  float cst = 0.f;
  __syncthreads();

  for (int step = 0; step < len; ++step) {
    const int pos = dir ? (len-1-step) : step;
    float xi=0.f, xf=0.f, xg=0.f, xo=0.f;
    if (t < H_) {
      const float* xr = xW + ((size_t)b*S_ + pos)*G4_ + t;
      xi = xr[0]; xf = xr[H_]; xg = xr[2*H_]; xo = xr[3*H_];
    }
    float a0 = 0.f, a1 = 0.f;
    #pragma unroll
    for (int j = 0; j < 25; ++j) {
      float4 h4 = *(const float4*)&hb[8*j];
      half2v p0 = __builtin_bit_cast(half2v, h4.x);
      half2v p1 = __builtin_bit_cast(half2v, h4.y);
      half2v p2 = __builtin_bit_cast(half2v, h4.z);
      half2v p3 = __builtin_bit_cast(half2v, h4.w);
      a0 = FDOT2(w0[4*j],   p0, a0);
      a0 = FDOT2(w0[4*j+1], p1, a0);
      a0 = FDOT2(w0[4*j+2], p2, a0);
      a0 = FDOT2(w0[4*j+3], p3, a0);
      a1 = FDOT2(w1[4*j],   p0, a1);
      a1 = FDOT2(w1[4*j+1], p1, a1);
      a1 = FDOT2(w1[4*j+2], p2, a1);
      a1 = FDOT2(w1[4*j+3], p3, a1);
    }
    sums[t] = a0;
    sums[512+t] = a1;
    __syncthreads();
    if (t < H_) {
      float gi = sums[t]        + xi;
      float gf = sums[H_ + t]   + xf;
      float gg = sums[2*H_ + t] + xg;
      float go = sums[3*H_ + t] + xo;
      float ig = 1.f/(1.f+__expf(-gi));
      float fg = 1.f/(1.f+__expf(-gf));
      float og = 1.f/(1.f+__expf(-go));
      float ggc = fminf(fmaxf(gg, -10.f), 10.f);
      float eg = __expf(2.f*ggc);
      cst = fg*cst + ig*((eg-1.f)/(eg+1.f));
      float cc = fminf(fmaxf(cst, -10.f), 10.f);
      float ec = __expf(2.f*cc);
      float hn = og*((ec-1.f)/(ec+1.f));
      hout[((size_t)b*S_ + pos)*H_ + t] = hn;
      hb[t] = (_Float16)hn;
    }
    __syncthreads();
  }
}

// -------- LSTM v5: w0 in regs (zero spill), w1 in LDS (replaces L2 spill) --------
// 512 thr, (512,2) -> 128-reg grant. Demand: w0 100 half2 + working ~28 = 128
// -> ~0 spill (vs ws's ~100 spilled regs refilled from L2 at 56B/clk, ~2800
// cyc/step). w1 (rows 512+t, t<288) lives in LDS: thread-major 16B chunks at
// (j*288+t)*16 — lane stride 4 words, each bank serves 8 words/read = full
// 128B/clk rate, ~900 cyc/step for 115KB. LDS total 119.8KB (1 WG/CU).
// Numerics identical to k_lstm_ws (absmax 0.0039, 4x validated).
__global__ __launch_bounds__(512, 2) void k_lstm_v5(
    const float* __restrict__ xWf, const float* __restrict__ xWb,
    const float* __restrict__ whhf, const float* __restrict__ whhb,
    const int* __restrict__ lengths,
    float* __restrict__ h_f, float* __restrict__ h_b)
{
  const int bid = blockIdx.x;
  const int dir = bid >> 5, b = bid & 31;
  const float* __restrict__ xW  = dir ? xWb : xWf;
  const float* __restrict__ whh = dir ? whhb : whhf;
  float* __restrict__ hout      = dir ? h_b : h_f;
  const int len = lengths[b];
  const int t = threadIdx.x;

  __shared__ __align__(16) _Float16 hb[256];         // 512B
  __shared__ float sums[1024];                       // 4KB
  __shared__ __align__(16) uint4 w1L[25*288];        // 115,200B

  // ---- preload: w0 -> regs; w1 (row 512+t, t<288) -> LDS 16B chunks ----
  half2v w0[100];
  {
    const float* r0p = whh + (size_t)t*H_;
    #pragma unroll
    for (int j = 0; j < 50; ++j) {
      float4 a = *(const float4*)(r0p + 4*j);
      w0[2*j]   = half2v{(_Float16)a.x, (_Float16)a.y};
      w0[2*j+1] = half2v{(_Float16)a.z, (_Float16)a.w};
    }
  }
  if (t < 288) {
    const float* r1p = whh + (size_t)(512+t)*H_;
    #pragma unroll
    for (int j4 = 0; j4 < 25; ++j4) {
      float4 a = *(const float4*)(r1p + 8*j4);
      float4 c = *(const float4*)(r1p + 8*j4 + 4);
      half2v q0{(_Float16)a.x, (_Float16)a.y};
      half2v q1{(_Float16)a.z, (_Float16)a.w};
      half2v q2{(_Float16)c.x, (_Float16)c.y};
      half2v q3{(_Float16)c.z, (_Float16)c.w};
      uint4 pk;
      pk.x = __builtin_bit_cast(unsigned int, q0);
      pk.y = __builtin_bit_cast(unsigned int, q1);
      pk.z = __builtin_bit_cast(unsigned int, q2);
      pk.w = __builtin_bit_cast(unsigned int, q3);
      w1L[j4*288 + t] = pk;
    }
  }

  if (t < 256) hb[t] = (_Float16)0.f;
  float cst = 0.f;
  __syncthreads();

  for (int step = 0; step < len; ++step) {
    const int pos = dir ? (len-1-step) : step;
    float xi=0.f, xf=0.f, xg=0.f, xo=0.f;
    if (t < H_) {
      const float* xr = xW + ((size_t)b*S_ + pos)*G4_ + t;
      xi = xr[0]; xf = xr[H_]; xg = xr[2*H_]; xo = xr[3*H_];
    }
    float a0 = 0.f, a1 = 0.f;
    if (t < 288) {
      #pragma unroll
      for (int j = 0; j < 25; ++j) {
        float4 h4 = *(const float4*)&hb[8*j];          // uniform broadcast
        half2v p0 = __builtin_bit_cast(half2v, h4.x);
        half2v p1 = __builtin_bit_cast(half2v, h4.y);
        half2v p2 = __builtin_bit_cast(half2v, h4.z);
        half2v p3 = __builtin_bit_cast(half2v, h4.w);
        uint4 wc = w1L[j*288 + t];                     // full-rate b128
        a0 = FDOT2(w0[4*j],   p0, a0);
        a0 = FDOT2(w0[4*j+1], p1, a0);
        a0 = FDOT2(w0[4*j+2], p2, a0);
        a0 = FDOT2(w0[4*j+3], p3, a0);
        a1 = FDOT2(__builtin_bit_cast(half2v, wc.x), p0, a1);
        a1 = FDOT2(__builtin_bit_cast(half2v, wc.y), p1, a1);
        a1 = FDOT2(__builtin_bit_cast(half2v, wc.z), p2, a1);
        a1 = FDOT2(__builtin_bit_cast(half2v, wc.w), p3, a1);
      }
    } else {
      #pragma unroll
      for (int j = 0; j < 25; ++j) {
        float4 h4 = *(const float4*)&hb[8*j];
        half2v p0 = __builtin_bit_cast(half2v, h4.x);
        half2v p1 = __builtin_bit_cast(half2v, h4.y);
        half2v p2 = __builtin_bit_cast(half2v, h4.z);
        half2v p3 = __builtin_bit_cast(half2v, h4.w);
        a0 = FDOT2(w0[4*j],   p0, a0);
        a0 = FDOT2(w0[4*j+1], p1, a0);
        a0 = FDOT2(w0[4*j+2], p2, a0);
        a0 = FDOT2(w0[4*j+3], p3, a0);
      }
    }
    sums[t] = a0;
    if (t < 288) sums[512+t] = a1;
    __syncthreads();
    if (t < H_) {
      float gi = sums[t]        + xi;
      float gf = sums[H_ + t]   + xf;
      float gg = sums[2*H_ + t] + xg;
      float go = sums[3*H_ + t] + xo;
      float ig = 1.f/(1.f+__expf(-gi));
      float fg = 1.f/(1.f+__expf(-gf));
      float og = 1.f/(1.f+__expf(-go));
      float ggc = fminf(fmaxf(gg, -10.f), 10.f);
      float eg = __expf(2.f*ggc);
      cst = fg*cst + ig*((eg-1.f)/(eg+1.f));
      float cc = fminf(fmaxf(cst, -10.f), 10.f);
      float ec = __expf(2.f*cc);
      float hn = og*((ec-1.f)/(ec+1.f));
      hout[((size_t)b*S_ + pos)*H_ + t] = hn;
      hb[t] = (_Float16)hn;
    }
    __syncthreads();
  }
}

// -------- scores --------
__global__ __launch_bounds__(256) void k_scores(
    const float* __restrict__ hf, const float* __restrict__ hb,
    const float* __restrict__ wkq, const int* __restrict__ lengths,
    float* __restrict__ theta)
{
  int wid = blockIdx.x*4 + (threadIdx.x >> 6);
  int lane = threadIdx.x & 63;
  int b = wid >> 9, s = wid & 511;
  const float* hfr = hf + ((size_t)b*S_ + s)*H_;
  const float* hbr = hb + ((size_t)b*S_ + s)*H_;
  bool valid = s < lengths[b];
  float a0=0.f, a1=0.f, a2=0.f, a3=0.f;
  if (valid) {
    for (int e = lane; e < ENC_; e += 64) {
      float hv = (e < H_) ? hfr[e] : hbr[e-H_];
      float4 w = *(const float4*)(wkq + e*4);
      a0 += hv*w.x; a1 += hv*w.y; a2 += hv*w.z; a3 += hv*w.w;
    }
    for (int off = 32; off; off >>= 1) {
      a0 += __shfl_xor(a0, off); a1 += __shfl_xor(a1, off);
      a2 += __shfl_xor(a2, off); a3 += __shfl_xor(a3, off);
    }
  }
  if (lane == 0) {
    size_t base = (size_t)b*2048 + s;
    theta[base       ] = valid ? SCALE_*a0 : NEGV;
    theta[base +  512] = valid ? SCALE_*a1 : NEGV;
    theta[base + 1024] = valid ? SCALE_*a2 : NEGV;
    theta[base + 1536] = valid ? SCALE_*a3 : NEGV;
  }
}

// -------- k_spzh: sparseMAP + z + hp + head fused, one block per b --------
__global__ __launch_bounds__(512) void k_spzh(
    const float* __restrict__ theta, const int* __restrict__ lengths,
    const float* __restrict__ hf, const float* __restrict__ hb,
    const float* __restrict__ Wv, const float* __restrict__ Wout,
    const float* __restrict__ Wh, const float* __restrict__ bh,
    float* __restrict__ out)
{
  const int b = blockIdx.x, t = threadIdx.x;
  __shared__ float muL[4][512];
  __shared__ float hpl[1600];
  __shared__ float ppl[ENC_];
  __shared__ float ojl[ENC_];
  __shared__ float red[512];
  const int len = lengths[b];

  if (t < 256) {
    const int head = t >> 6, lane = t & 63;
    const float* th = theta + ((size_t)b*4 + head)*512;
    float v[8];
    #pragma unroll
    for (int i = 0; i < 8; ++i) v[i] = th[i*64 + lane];
    float kf = rintf(0.2f * (float)len);
    float mn = v[0], mx = v[0];
    #pragma unroll
    for (int i = 1; i < 8; ++i) { mn = fminf(mn, v[i]); mx = fmaxf(mx, v[i]); }
    for (int off = 32; off; off >>= 1) {
      mn = fminf(mn, __shfl_xor(mn, off)); mx = fmaxf(mx, __shfl_xor(mx, off));
    }
    float lo = mn - 1.f, hi = mx;
    for (int it = 0; it < 60; ++it) {
      float mid = 0.5f*(lo + hi);
      float s = 0.f;
      #pragma unroll
      for (int i = 0; i < 8; ++i) s += fminf(fmaxf(v[i]-mid, 0.f), 1.f);
      for (int off = 32; off; off >>= 1) s += __shfl_xor(s, off);
      bool big = s > kf;
      lo = big ? mid : lo;
      hi = big ? hi : mid;
    }
    float tau0 = 0.5f*(lo + hi);
    float fs = 0.f, nU = 0.f, nS = 0.f;
    #pragma unroll
    for (int i = 0; i < 8; ++i) {
      float m0 = v[i] - tau0;
      if (m0 >= 1.f) nU += 1.f;
      else if (m0 > 0.f) { fs += v[i]; nS += 1.f; }
    }
    for (int off = 32; off; off >>= 1) {
      fs += __shfl_xor(fs, off); nU += __shfl_xor(nU, off); nS += __shfl_xor(nS, off);
    }
    float tau = (fs + nU - kf) / fmaxf(nS, 1.f);
    tau = (nS > 0.f) ? tau : tau0;
    #pragma unroll
    for (int i = 0; i < 8; ++i)
      muL[head][i*64 + lane] = fminf(fmaxf(v[i]-tau, 0.f), 1.f);
  }
  __syncthreads();

  {
    const int s = t;
    float zz = (s < len) ? 0.25f*(muL[0][s]+muL[1][s]+muL[2][s]+muL[3][s]) : 0.f;
    out[32 + b*S_ + s] = zz;
  }

  if (t < ENC_) {
    const float* hsrc = (t < H_) ? (hf + t) : (hb + (t - H_));
    float ac0 = 0.f, ac1 = 0.f, ac2 = 0.f, ac3 = 0.f;
    for (int s = 0; s < S_; ++s) {
      float hv = hsrc[((size_t)b*S_ + s)*H_];
      ac0 += muL[0][s]*hv; ac1 += muL[1][s]*hv;
      ac2 += muL[2][s]*hv; ac3 += muL[3][s]*hv;
    }
    hpl[t]        = ac0;
    hpl[400 + t]  = ac1;
    hpl[800 + t]  = ac2;
    hpl[1200 + t] = ac3;
  }
  __syncthreads();

  if (t < ENC_) {
    int head = t / 100;
    float acc = 0.f;
    for (int e = 0; e < ENC_; ++e) acc += hpl[head*ENC_ + e] * Wv[(size_t)e*ENC_ + t];
    ppl[t] = acc;
  }
  __syncthreads();
  if (t < ENC_) {
    float acc = 0.f;
    for (int c = 0; c < ENC_; ++c) acc += ppl[c] * Wout[(size_t)c*ENC_ + t];
    ojl[t] = acc;
  }
  __syncthreads();
  red[t] = (t < ENC_) ? ojl[t]*Wh[t] : 0.f;
  __syncthreads();
  for (int sft = 256; sft; sft >>= 1) {
    if (t < sft) red[t] += red[t+sft];
    __syncthreads();
  }
  if (t == 0) out[b] = 1.f/(1.f + expf(-(red[0] + bh[0])));
}

extern "C" void kernel_launch(void* const* d_in, const int* in_sizes, int n_in,
                              void* d_out, int out_size, void* d_ws, size_t ws_size,
                              hipStream_t stream) {
  const int*   x    = (const int*)d_in[0];
  const void*  mask = d_in[1];
  const float* emb  = (const float*)d_in[2];
  const float* wihf = (const float*)d_in[3];
  const float* whhf = (const float*)d_in[4];
  const float* bf   = (const float*)d_in[5];
  const float* wihb = (const float*)d_in[6];
  const float* whhb = (const float*)d_in[7];
  const float* bb   = (const float*)d_in[8];
  const float* qs   = (const float*)d_in[9];
  const float* Wq   = (const float*)d_in[10];
  const float* Wk   = (const float*)d_in[11];
  const float* Wv   = (const float*)d_in[12];
  const float* Wout = (const float*)d_in[13];
  const float* Wh   = (const float*)d_in[14];
  const float* bh   = (const float*)d_in[15];
  float* out = (float*)d_out;
  float* W = (float*)d_ws;
  int* lengths = (int*)(W + OF_LEN);

  // Gate: use v5 only if near-spill-free (<=32 regs scratch). The fallback is
  // the measured-best 645us k_lstm_ws, so worst case == round 16.
  hipFuncAttributes fa{};
  bool use_v5 = false;
  if (hipFuncGetAttributes(&fa, (const void*)k_lstm_v5) == hipSuccess)
    use_v5 = (fa.localSizeBytes <= 128);

  k_prep<<<39, 256, 0, stream>>>(mask, lengths, qs, Wq, Wk, W+OF_WKQ);
  k_gemm_mfma<<<dim3(128, 25), 256, 0, stream>>>(x, emb, wihf, wihb, bf, bb,
                                                 W+OF_XWF, W+OF_XWB);
  if (use_v5)
    k_lstm_v5<<<64, 512, 0, stream>>>(W+OF_XWF, W+OF_XWB, whhf, whhb,
                                      lengths, W+OF_HF, W+OF_HB);
  else
    k_lstm_ws<<<64, 512, 0, stream>>>(W+OF_XWF, W+OF_XWB, whhf, whhb,
                                      lengths, W+OF_HF, W+OF_HB);
  k_scores<<<4096, 256, 0, stream>>>(W+OF_HF, W+OF_HB, W+OF_WKQ, lengths, W+OF_THETA);
  k_spzh<<<32, 512, 0, stream>>>(W+OF_THETA, lengths, W+OF_HF, W+OF_HB,
                                 Wv, Wout, Wh, bh, out);
}

// Round 18
// 997.880 us; speedup vs baseline: 1.1031x; 1.1031x over previous
//
#include <hip/hip_runtime.h>
#include <hip/hip_bf16.h>
#include <math.h>

// Problem constants
#define B_   32
#define S_   512
#define V_   30000
#define E_   300
#define H_   200
#define NH_  4
#define ENC_ 400
#define G4_  800     // 4*H
#define NEGV  (-1e9f)
#define SCALE_ 1000.0f

typedef _Float16 half2v __attribute__((ext_vector_type(2)));
typedef _Float16 f16x8  __attribute__((ext_vector_type(8)));
typedef float    f32x4  __attribute__((ext_vector_type(4)));

#if defined(__has_builtin)
#if __has_builtin(__builtin_amdgcn_fdot2)
#define FDOT2(a,b,c) __builtin_amdgcn_fdot2((a),(b),(c),false)
#endif
#endif
#ifndef FDOT2
#define FDOT2(a,b,c) fmaf((float)(a)[1],(float)(b)[1], fmaf((float)(a)[0],(float)(b)[0],(c)))
#endif

// ---- workspace layout (float offsets) ----
#define OF_WKQ   320448ull     // wkq [400][4]
#define OF_THETA 322048ull     // theta [B][4][512]
#define OF_LEN   504320ull     // lengths (int) [32]
#define OF_XWF   504384ull     // xW forward  [B*S][800]
#define OF_XWB   13611584ull   // xW backward [B*S][800]
#define OF_HF    26718784ull   // h_f [B*S][200]
#define OF_HB    29995584ull   // h_b [B*S][200]

// -------- k_prep: lengths (blocks 0..31) + wkq with in-block qvec (32..38) --------
__global__ __launch_bounds__(256) void k_prep(
    const void* __restrict__ mask, int* __restrict__ lengths,
    const float* __restrict__ qs, const float* __restrict__ Wq,
    const float* __restrict__ Wk, float* __restrict__ wkq)
{
  const int blk = blockIdx.x, t = threadIdx.x;
  __shared__ float shb[800];
  if (blk < 32) {
    int* red = (int*)shb;
    const unsigned char* mb = (const unsigned char*)mask;
    int mode;
    if (mb[1] != 0) mode = 0;
    else if (((const int*)mask)[1] != 0) mode = 1;
    else mode = 2;
    int cnt = 0;
    for (int s = t; s < S_; s += 256) {
      int v;
      if (mode == 0)      v = mb[blk*S_ + s] ? 1 : 0;
      else if (mode == 1) v = ((const int*)mask)[blk*S_ + s] ? 1 : 0;
      else                v = ((const long long*)mask)[blk*S_ + s] ? 1 : 0;
      cnt += v;
    }
    red[t] = cnt;
    __syncthreads();
    for (int sft = 128; sft; sft >>= 1) {
      if (t < sft) red[t] += red[t+sft];
      __syncthreads();
    }
    if (t == 0) lengths[blk] = red[0];
  } else {
    float* qsl = shb;              // [400]
    float* qv  = shb + 400;        // [400]
    if (t < ENC_) qsl[t] = qs[t];
    if (t + 256 < ENC_) qsl[t+256] = qs[t+256];
    __syncthreads();
    {
      float acc = 0.f;
      for (int i = 0; i < ENC_; ++i) acc += qsl[i] * Wq[(size_t)i*ENC_ + t];
      qv[t] = acc;
      if (t + 256 < ENC_) {
        float acc2 = 0.f;
        for (int i = 0; i < ENC_; ++i) acc2 += qsl[i] * Wq[(size_t)i*ENC_ + t + 256];
        qv[t+256] = acc2;
      }
    }
    __syncthreads();
    const int e = (blk - 32)*64 + (t >> 2);
    const int head = t & 3;
    if (e < ENC_) {
      float acc = 0.f;
      const float* row = Wk + (size_t)e*ENC_ + head*100;
      const float* qvh = qv + head*100;
      for (int d = 0; d < 100; ++d) acc += row[d]*qvh[d];
      wkq[e*4 + head] = acc;
    }
  }
}

// -------- input projections via fp16 MFMA (builtins only; passing) --------
__global__ __launch_bounds__(256) void k_gemm_mfma(
    const int* __restrict__ x, const float* __restrict__ emb,
    const float* __restrict__ wf, const float* __restrict__ wb,
    const float* __restrict__ bf, const float* __restrict__ bb,
    float* __restrict__ xWf, float* __restrict__ xWb)
{
  __shared__ int xid[128];
  __shared__ __align__(16) _Float16 sA[128][40];
  __shared__ __align__(16) _Float16 sB[64][40];
  const int t = threadIdx.x;
  const int row0 = blockIdx.x * 128;
  const int col0 = blockIdx.y * 64;
  if (t < 128) xid[t] = x[row0 + t];
  const int w = t >> 6, lane = t & 63;
  const int wr = w >> 1, wc = w & 1;
  f32x4 acc[4][2] = {};
  const int ar = t >> 1, ah = t & 1;
  const int bc = t >> 2, bq = t & 3;
  const int colg = col0 + bc;
  const float* wsrc = (colg < 800) ? (wf + (size_t)colg*300)
                                   : (wb + (size_t)(colg-800)*300);
  __syncthreads();
  const float* asrc = emb + (size_t)xid[ar]*300;
  for (int kc = 0; kc < 10; ++kc) {
    const int k0 = kc*32;
    {
      const int kb = k0 + ah*16;
      _Float16 tmp[16];
      if (kb + 15 < 300) {
        #pragma unroll
        for (int q = 0; q < 4; ++q) {
          float4 a = *(const float4*)(asrc + kb + 4*q);
          tmp[4*q]  =(_Float16)a.x; tmp[4*q+1]=(_Float16)a.y;
          tmp[4*q+2]=(_Float16)a.z; tmp[4*q+3]=(_Float16)a.w;
        }
      } else {
        #pragma unroll
        for (int i = 0; i < 16; ++i)
          tmp[i] = (_Float16)((kb+i < 300) ? asrc[kb+i] : 0.f);
      }
      *(f16x8*)&sA[ar][ah*16]   = *(f16x8*)&tmp[0];
      *(f16x8*)&sA[ar][ah*16+8] = *(f16x8*)&tmp[8];
    }
    {
      const int kb = k0 + bq*8;
      _Float16 tmp[8];
      if (kb + 7 < 300) {
        #pragma unroll
        for (int q = 0; q < 2; ++q) {
          float4 a = *(const float4*)(wsrc + kb + 4*q);
          tmp[4*q]  =(_Float16)a.x; tmp[4*q+1]=(_Float16)a.y;
          tmp[4*q+2]=(_Float16)a.z; tmp[4*q+3]=(_Float16)a.w;
        }
      } else {
        #pragma unroll
        for (int i = 0; i < 8; ++i)
          tmp[i] = (_Float16)((kb+i < 300) ? wsrc[kb+i] : 0.f);
      }
      *(f16x8*)&sB[bc][bq*8] = *(f16x8*)&tmp[0];
    }
    __syncthreads();
    const int fr = lane & 15, kg = lane >> 4;
    f16x8 b0 = *(const f16x8*)&sB[wc*32 + fr][kg*8];
    f16x8 b1 = *(const f16x8*)&sB[wc*32 + 16 + fr][kg*8];
    #pragma unroll
    for (int m = 0; m < 4; ++m) {
      f16x8 afrag = *(const f16x8*)&sA[wr*64 + m*16 + fr][kg*8];
      acc[m][0] = __builtin_amdgcn_mfma_f32_16x16x32_f16(afrag, b0, acc[m][0], 0,0,0);
      acc[m][1] = __builtin_amdgcn_mfma_f32_16x16x32_f16(afrag, b1, acc[m][1], 0,0,0);
    }
    __syncthreads();
  }
  const int crb = (lane >> 4) * 4, ccol = lane & 15;
  #pragma unroll
  for (int n = 0; n < 2; ++n) {
    int colg2 = col0 + wc*32 + n*16 + ccol;
    bool isF = colg2 < 800;
    int colo = isF ? colg2 : colg2 - 800;
    float bias = isF ? bf[colo] : bb[colo];
    float* dst = isF ? xWf : xWb;
    #pragma unroll
    for (int m = 0; m < 4; ++m) {
      int row = row0 + wr*64 + m*16 + crb;
      #pragma unroll
      for (int r = 0; r < 4; ++r)
        dst[(size_t)(row+r)*800 + colo] = acc[m][n][r] + bias;
    }
  }
}

// -------- fallback LSTM — round-3 k_lstm_ws verbatim (measured 645 us) --------
__global__ __launch_bounds__(512, 2) void k_lstm_ws(
    const float* __restrict__ xWf, const float* __restrict__ xWb,
    const float* __restrict__ whhf, const float* __restrict__ whhb,
    const int* __restrict__ lengths,
    float* __restrict__ h_f, float* __restrict__ h_b)
{
  const int bid = blockIdx.x;
  const int dir = bid >> 5, b = bid & 31;
  const float* __restrict__ xW  = dir ? xWb : xWf;
  const float* __restrict__ whh = dir ? whhb : whhf;
  float* __restrict__ hout      = dir ? h_b : h_f;
  const int len = lengths[b];
  const int t = threadIdx.x;

  __shared__ __align__(16) _Float16 hb[256];
  __shared__ float sums[1024];

  half2v w0[100], w1[100];
  {
    const float* r0p = whh + (size_t)t*H_;
    #pragma unroll
    for (int j = 0; j < 50; ++j) {
      float4 a = *(const float4*)(r0p + 4*j);
      w0[2*j]   = half2v{(_Float16)a.x, (_Float16)a.y};
      w0[2*j+1] = half2v{(_Float16)a.z, (_Float16)a.w};
    }
    if (t < 288) {
      const float* r1p = whh + (size_t)(512+t)*H_;
      #pragma unroll
      for (int j = 0; j < 50; ++j) {
        float4 a = *(const float4*)(r1p + 4*j);
        w1[2*j]   = half2v{(_Float16)a.x, (_Float16)a.y};
        w1[2*j+1] = half2v{(_Float16)a.z, (_Float16)a.w};
      }
    } else {
      #pragma unroll
      for (int j = 0; j < 100; ++j) w1[j] = half2v{(_Float16)0.f, (_Float16)0.f};
    }
  }

  if (t < 256) hb[t] = (_Float16)0.f;
  float cst = 0.f;
  __syncthreads();

  for (int step = 0; step < len; ++step) {
    const int pos = dir ? (len-1-step) : step;
    float xi=0.f, xf=0.f, xg=0.f, xo=0.f;
    if (t < H_) {
      const float* xr = xW + ((size_t)b*S_ + pos)*G4_ + t;
      xi = xr[0]; xf = xr[H_]; xg = xr[2*H_]; xo = xr[3*H_];
    }
    float a0 = 0.f, a1 = 0.f;
    #pragma unroll
    for (int j = 0; j < 25; ++j) {
      float4 h4 = *(const float4*)&hb[8*j];
      half2v p0 = __builtin_bit_cast(half2v, h4.x);
      half2v p1 = __builtin_bit_cast(half2v, h4.y);
      half2v p2 = __builtin_bit_cast(half2v, h4.z);
      half2v p3 = __builtin_bit_cast(half2v, h4.w);
      a0 = FDOT2(w0[4*j],   p0, a0);
      a0 = FDOT2(w0[4*j+1], p1, a0);
      a0 = FDOT2(w0[4*j+2], p2, a0);
      a0 = FDOT2(w0[4*j+3], p3, a0);
      a1 = FDOT2(w1[4*j],   p0, a1);
      a1 = FDOT2(w1[4*j+1], p1, a1);
      a1 = FDOT2(w1[4*j+2], p2, a1);
      a1 = FDOT2(w1[4*j+3], p3, a1);
    }
    sums[t] = a0;
    sums[512+t] = a1;
    __syncthreads();
    if (t < H_) {
      float gi = sums[t]        + xi;
      float gf = sums[H_ + t]   + xf;
      float gg = sums[2*H_ + t] + xg;
      float go = sums[3*H_ + t] + xo;
      float ig = 1.f/(1.f+__expf(-gi));
      float fg = 1.f/(1.f+__expf(-gf));
      float og = 1.f/(1.f+__expf(-go));
      float ggc = fminf(fmaxf(gg, -10.f), 10.f);
      float eg = __expf(2.f*ggc);
      cst = fg*cst + ig*((eg-1.f)/(eg+1.f));
      float cc = fminf(fmaxf(cst, -10.f), 10.f);
      float ec = __expf(2.f*cc);
      float hn = og*((ec-1.f)/(ec+1.f));
      hout[((size_t)b*S_ + pos)*H_ + t] = hn;
      hb[t] = (_Float16)hn;
    }
    __syncthreads();
  }
}

// -------- LSTM v6: three-tier weights — regs(w0) / LDS(w1 j<12) / scratch(rest) --------
// Pipe-balance theory: ws(645us) = LDS~600 + scratch-refill~2800 + VALU~1500;
// v5(925us) = everything on LDS. v6 splits w1: 12 uint4-chunks in LDS
// (55.3KB, conflict-free thread-major), 13 chunks (52 half2) left to regs ->
// ~52 spilled -> refill ~1430 cyc. Targets refill ~ LDS ~ VALU ~ 1400-1500,
// three overlapping streams. Numerics identical to k_lstm_ws.
__global__ __launch_bounds__(512, 2) void k_lstm_v6(
    const float* __restrict__ xWf, const float* __restrict__ xWb,
    const float* __restrict__ whhf, const float* __restrict__ whhb,
    const int* __restrict__ lengths,
    float* __restrict__ h_f, float* __restrict__ h_b)
{
  const int bid = blockIdx.x;
  const int dir = bid >> 5, b = bid & 31;
  const float* __restrict__ xW  = dir ? xWb : xWf;
  const float* __restrict__ whh = dir ? whhb : whhf;
  float* __restrict__ hout      = dir ? h_b : h_f;
  const int len = lengths[b];
  const int t = threadIdx.x;

  __shared__ __align__(16) _Float16 hb[256];         // 512B
  __shared__ float sums[1024];                       // 4KB
  __shared__ __align__(16) uint4 w1L[12*288];        // 55,296B  (j = 0..11)

  // ---- preload ----
  half2v w0[100];                                    // rows t, all k
  {
    const float* r0p = whh + (size_t)t*H_;
    #pragma unroll
    for (int j = 0; j < 50; ++j) {
      float4 a = *(const float4*)(r0p + 4*j);
      w0[2*j]   = half2v{(_Float16)a.x, (_Float16)a.y};
      w0[2*j+1] = half2v{(_Float16)a.z, (_Float16)a.w};
    }
  }
  half2v w1r[52];                                    // rows 512+t, k-chunks j=12..24
  if (t < 288) {
    const float* r1p = whh + (size_t)(512+t)*H_;
    // LDS part: j = 0..11  (k = 8j..8j+7)
    #pragma unroll
    for (int j4 = 0; j4 < 12; ++j4) {
      float4 a = *(const float4*)(r1p + 8*j4);
      float4 c = *(const float4*)(r1p + 8*j4 + 4);
      half2v q0{(_Float16)a.x, (_Float16)a.y};
      half2v q1{(_Float16)a.z, (_Float16)a.w};
      half2v q2{(_Float16)c.x, (_Float16)c.y};
      half2v q3{(_Float16)c.z, (_Float16)c.w};
      uint4 pk;
      pk.x = __builtin_bit_cast(unsigned int, q0);
      pk.y = __builtin_bit_cast(unsigned int, q1);
      pk.z = __builtin_bit_cast(unsigned int, q2);
      pk.w = __builtin_bit_cast(unsigned int, q3);
      w1L[j4*288 + t] = pk;
    }
    // Register/scratch part: j = 12..24 -> w1r[(j-12)*4 + m]
    #pragma unroll
    for (int j = 12; j < 25; ++j) {
      float4 a = *(const float4*)(r1p + 8*j);
      float4 c = *(const float4*)(r1p + 8*j + 4);
      w1r[(j-12)*4 + 0] = half2v{(_Float16)a.x, (_Float16)a.y};
      w1r[(j-12)*4 + 1] = half2v{(_Float16)a.z, (_Float16)a.w};
      w1r[(j-12)*4 + 2] = half2v{(_Float16)c.x, (_Float16)c.y};
      w1r[(j-12)*4 + 3] = half2v{(_Float16)c.z, (_Float16)c.w};
    }
  } else {
    #pragma unroll
    for (int m = 0; m < 52; ++m) w1r[m] = half2v{(_Float16)0.f, (_Float16)0.f};
  }

  if (t < 256) hb[t] = (_Float16)0.f;
  float cst = 0.f;
  __syncthreads();

  for (int step = 0; step < len; ++step) {
    const int pos = dir ? (len-1-step) : step;
    float xi=0.f, xf=0.f, xg=0.f, xo=0.f;
    if (t < H_) {
      const float* xr = xW + ((size_t)b*S_ + pos)*G4_ + t;
      xi = xr[0]; xf = xr[H_]; xg = xr[2*H_]; xo = xr[3*H_];
    }
    float a0 = 0.f, a1 = 0.f;
    const bool has2 = (t < 288);
    // j = 0..11: w0 from regs, w1 from LDS
    #pragma unroll
    for (int j = 0; j < 12; ++j) {
      float4 h4 = *(const float4*)&hb[8*j];          // uniform broadcast
      half2v p0 = __builtin_bit_cast(half2v, h4.x);
      half2v p1 = __builtin_bit_cast(half2v, h4.y);
      half2v p2 = __builtin_bit_cast(half2v, h4.z);
      half2v p3 = __builtin_bit_cast(half2v, h4.w);
      a0 = FDOT2(w0[4*j],   p0, a0);
      a0 = FDOT2(w0[4*j+1], p1, a0);
      a0 = FDOT2(w0[4*j+2], p2, a0);
      a0 = FDOT2(w0[4*j+3], p3, a0);
      if (has2) {
        uint4 wc = w1L[j*288 + t];                   // full-rate b128
        a1 = FDOT2(__builtin_bit_cast(half2v, wc.x), p0, a1);
        a1 = FDOT2(__builtin_bit_cast(half2v, wc.y), p1, a1);
        a1 = FDOT2(__builtin_bit_cast(half2v, wc.z), p2, a1);
        a1 = FDOT2(__builtin_bit_cast(half2v, wc.w), p3, a1);
      }
    }
    // j = 12..24: both from regs (w1r side spills ~52 -> scratch/L2 refill)
    #pragma unroll
    for (int j = 12; j < 25; ++j) {
      float4 h4 = *(const float4*)&hb[8*j];
      half2v p0 = __builtin_bit_cast(half2v, h4.x);
      half2v p1 = __builtin_bit_cast(half2v, h4.y);
      half2v p2 = __builtin_bit_cast(half2v, h4.z);
      half2v p3 = __builtin_bit_cast(half2v, h4.w);
      a0 = FDOT2(w0[4*j],   p0, a0);
      a0 = FDOT2(w0[4*j+1], p1, a0);
      a0 = FDOT2(w0[4*j+2], p2, a0);
      a0 = FDOT2(w0[4*j+3], p3, a0);
      a1 = FDOT2(w1r[(j-12)*4 + 0], p0, a1);
      a1 = FDOT2(w1r[(j-12)*4 + 1], p1, a1);
      a1 = FDOT2(w1r[(j-12)*4 + 2], p2, a1);
      a1 = FDOT2(w1r[(j-12)*4 + 3], p3, a1);
    }
    sums[t] = a0;
    sums[512+t] = a1;
    __syncthreads();
    if (t < H_) {
      float gi = sums[t]        + xi;
      float gf = sums[H_ + t]   + xf;
      float gg = sums[2*H_ + t] + xg;
      float go = sums[3*H_ + t] + xo;
      float ig = 1.f/(1.f+__expf(-gi));
      float fg = 1.f/(1.f+__expf(-gf));
      float og = 1.f/(1.f+__expf(-go));
      float ggc = fminf(fmaxf(gg, -10.f), 10.f);
      float eg = __expf(2.f*ggc);
      cst = fg*cst + ig*((eg-1.f)/(eg+1.f));
      float cc = fminf(fmaxf(cst, -10.f), 10.f);
      float ec = __expf(2.f*cc);
      float hn = og*((ec-1.f)/(ec+1.f));
      hout[((size_t)b*S_ + pos)*H_ + t] = hn;
      hb[t] = (_Float16)hn;
    }
    __syncthreads();
  }
}

// -------- scores --------
__global__ __launch_bounds__(256) void k_scores(
    const float* __restrict__ hf, const float* __restrict__ hb,
    const float* __restrict__ wkq, const int* __restrict__ lengths,
    float* __restrict__ theta)
{
  int wid = blockIdx.x*4 + (threadIdx.x >> 6);
  int lane = threadIdx.x & 63;
  int b = wid >> 9, s = wid & 511;
  const float* hfr = hf + ((size_t)b*S_ + s)*H_;
  const float* hbr = hb + ((size_t)b*S_ + s)*H_;
  bool valid = s < lengths[b];
  float a0=0.f, a1=0.f, a2=0.f, a3=0.f;
  if (valid) {
    for (int e = lane; e < ENC_; e += 64) {
      float hv = (e < H_) ? hfr[e] : hbr[e-H_];
      float4 w = *(const float4*)(wkq + e*4);
      a0 += hv*w.x; a1 += hv*w.y; a2 += hv*w.z; a3 += hv*w.w;
    }
    for (int off = 32; off; off >>= 1) {
      a0 += __shfl_xor(a0, off); a1 += __shfl_xor(a1, off);
      a2 += __shfl_xor(a2, off); a3 += __shfl_xor(a3, off);
    }
  }
  if (lane == 0) {
    size_t base = (size_t)b*2048 + s;
    theta[base       ] = valid ? SCALE_*a0 : NEGV;
    theta[base +  512] = valid ? SCALE_*a1 : NEGV;
    theta[base + 1024] = valid ? SCALE_*a2 : NEGV;
    theta[base + 1536] = valid ? SCALE_*a3 : NEGV;
  }
}

// -------- k_spzh: sparseMAP + z + hp + head fused, one block per b --------
__global__ __launch_bounds__(512) void k_spzh(
    const float* __restrict__ theta, const int* __restrict__ lengths,
    const float* __restrict__ hf, const float* __restrict__ hb,
    const float* __restrict__ Wv, const float* __restrict__ Wout,
    const float* __restrict__ Wh, const float* __restrict__ bh,
    float* __restrict__ out)
{
  const int b = blockIdx.x, t = threadIdx.x;
  __shared__ float muL[4][512];
  __shared__ float hpl[1600];
  __shared__ float ppl[ENC_];
  __shared__ float ojl[ENC_];
  __shared__ float red[512];
  const int len = lengths[b];

  if (t < 256) {
    const int head = t >> 6, lane = t & 63;
    const float* th = theta + ((size_t)b*4 + head)*512;
    float v[8];
    #pragma unroll
    for (int i = 0; i < 8; ++i) v[i] = th[i*64 + lane];
    float kf = rintf(0.2f * (float)len);
    float mn = v[0], mx = v[0];
    #pragma unroll
    for (int i = 1; i < 8; ++i) { mn = fminf(mn, v[i]); mx = fmaxf(mx, v[i]); }
    for (int off = 32; off; off >>= 1) {
      mn = fminf(mn, __shfl_xor(mn, off)); mx = fmaxf(mx, __shfl_xor(mx, off));
    }
    float lo = mn - 1.f, hi = mx;
    for (int it = 0; it < 60; ++it) {
      float mid = 0.5f*(lo + hi);
      float s = 0.f;
      #pragma unroll
      for (int i = 0; i < 8; ++i) s += fminf(fmaxf(v[i]-mid, 0.f), 1.f);
      for (int off = 32; off; off >>= 1) s += __shfl_xor(s, off);
      bool big = s > kf;
      lo = big ? mid : lo;
      hi = big ? hi : mid;
    }
    float tau0 = 0.5f*(lo + hi);
    float fs = 0.f, nU = 0.f, nS = 0.f;
    #pragma unroll
    for (int i = 0; i < 8; ++i) {
      float m0 = v[i] - tau0;
      if (m0 >= 1.f) nU += 1.f;
      else if (m0 > 0.f) { fs += v[i]; nS += 1.f; }
    }
    for (int off = 32; off; off >>= 1) {
      fs += __shfl_xor(fs, off); nU += __shfl_xor(nU, off); nS += __shfl_xor(nS, off);
    }
    float tau = (fs + nU - kf) / fmaxf(nS, 1.f);
    tau = (nS > 0.f) ? tau : tau0;
    #pragma unroll
    for (int i = 0; i < 8; ++i)
      muL[head][i*64 + lane] = fminf(fmaxf(v[i]-tau, 0.f), 1.f);
  }
  __syncthreads();

  {
    const int s = t;
    float zz = (s < len) ? 0.25f*(muL[0][s]+muL[1][s]+muL[2][s]+muL[3][s]) : 0.f;
    out[32 + b*S_ + s] = zz;
  }

  if (t < ENC_) {
    const float* hsrc = (t < H_) ? (hf + t) : (hb + (t - H_));
    float ac0 = 0.f, ac1 = 0.f, ac2 = 0.f, ac3 = 0.f;
    for (int s = 0; s < S_; ++s) {
      float hv = hsrc[((size_t)b*S_ + s)*H_];
      ac0 += muL[0][s]*hv; ac1 += muL[1][s]*hv;
      ac2 += muL[2][s]*hv; ac3 += muL[3][s]*hv;
    }
    hpl[t]        = ac0;
    hpl[400 + t]  = ac1;
    hpl[800 + t]  = ac2;
    hpl[1200 + t] = ac3;
  }
  __syncthreads();

  if (t < ENC_) {
    int head = t / 100;
    float acc = 0.f;
    for (int e = 0; e < ENC_; ++e) acc += hpl[head*ENC_ + e] * Wv[(size_t)e*ENC_ + t];
    ppl[t] = acc;
  }
  __syncthreads();
  if (t < ENC_) {
    float acc = 0.f;
    for (int c = 0; c < ENC_; ++c) acc += ppl[c] * Wout[(size_t)c*ENC_ + t];
    ojl[t] = acc;
  }
  __syncthreads();
  red[t] = (t < ENC_) ? ojl[t]*Wh[t] : 0.f;
  __syncthreads();
  for (int sft = 256; sft; sft >>= 1) {
    if (t < sft) red[t] += red[t+sft];
    __syncthreads();
  }
  if (t == 0) out[b] = 1.f/(1.f + expf(-(red[0] + bh[0])));
}

extern "C" void kernel_launch(void* const* d_in, const int* in_sizes, int n_in,
                              void* d_out, int out_size, void* d_ws, size_t ws_size,
                              hipStream_t stream) {
  const int*   x    = (const int*)d_in[0];
  const void*  mask = d_in[1];
  const float* emb  = (const float*)d_in[2];
  const float* wihf = (const float*)d_in[3];
  const float* whhf = (const float*)d_in[4];
  const float* bf   = (const float*)d_in[5];
  const float* wihb = (const float*)d_in[6];
  const float* whhb = (const float*)d_in[7];
  const float* bb   = (const float*)d_in[8];
  const float* qs   = (const float*)d_in[9];
  const float* Wq   = (const float*)d_in[10];
  const float* Wk   = (const float*)d_in[11];
  const float* Wv   = (const float*)d_in[12];
  const float* Wout = (const float*)d_in[13];
  const float* Wh   = (const float*)d_in[14];
  const float* bh   = (const float*)d_in[15];
  float* out = (float*)d_out;
  float* W = (float*)d_ws;
  int* lengths = (int*)(W + OF_LEN);

  // Gate: v6 should spill SOME (it's designed to: ~52 regs = 208B) but not
  // explode (>300B means allocator gave < expected grant). Outside band ->
  // measured-best 645us fallback.
  hipFuncAttributes fa{};
  bool use_v6 = false;
  if (hipFuncGetAttributes(&fa, (const void*)k_lstm_v6) == hipSuccess)
    use_v6 = (fa.localSizeBytes <= 300);

  k_prep<<<39, 256, 0, stream>>>(mask, lengths, qs, Wq, Wk, W+OF_WKQ);
  k_gemm_mfma<<<dim3(128, 25), 256, 0, stream>>>(x, emb, wihf, wihb, bf, bb,
                                                 W+OF_XWF, W+OF_XWB);
  if (use_v6)
    k_lstm_v6<<<64, 512, 0, stream>>>(W+OF_XWF, W+OF_XWB, whhf, whhb,
                                      lengths, W+OF_HF, W+OF_HB);
  else
    k_lstm_ws<<<64, 512, 0, stream>>>(W+OF_XWF, W+OF_XWB, whhf, whhb,
                                      lengths, W+OF_HF, W+OF_HB);
  k_scores<<<4096, 256, 0, stream>>>(W+OF_HF, W+OF_HB, W+OF_WKQ, lengths, W+OF_THETA);
  k_spzh<<<32, 512, 0, stream>>>(W+OF_THETA, lengths, W+OF_HF, W+OF_HB,
                                 Wv, Wout, Wh, bh, out);
}

// Round 19
// 828.321 us; speedup vs baseline: 1.3289x; 1.2047x over previous
//
#include <hip/hip_runtime.h>
#include <hip/hip_bf16.h>
#include <math.h>

// Problem constants
#define B_   32
#define S_   512
#define V_   30000
#define E_   300
#define H_   200
#define NH_  4
#define ENC_ 400
#define G4_  800     // 4*H
#define NEGV  (-1e9f)
#define SCALE_ 1000.0f

typedef _Float16 half2v __attribute__((ext_vector_type(2)));
typedef _Float16 f16x8  __attribute__((ext_vector_type(8)));
typedef float    f32x4  __attribute__((ext_vector_type(4)));

#if defined(__has_builtin)
#if __has_builtin(__builtin_amdgcn_fdot2)
#define FDOT2(a,b,c) __builtin_amdgcn_fdot2((a),(b),(c),false)
#endif
#endif
#ifndef FDOT2
#define FDOT2(a,b,c) fmaf((float)(a)[1],(float)(b)[1], fmaf((float)(a)[0],(float)(b)[0],(c)))
#endif

// ---- workspace layout (float offsets) ----
#define OF_WKQ   320448ull     // wkq [400][4]
#define OF_THETA 322048ull     // theta [B][4][512]
#define OF_LEN   504320ull     // lengths (int) [32]
#define OF_XWF   504384ull     // xW forward  [B*S][800]
#define OF_XWB   13611584ull   // xW backward [B*S][800]
#define OF_HF    26718784ull   // h_f [B*S][200]
#define OF_HB    29995584ull   // h_b [B*S][200]

// -------- k_prep: lengths (blocks 0..31) + wkq with in-block qvec (32..38) --------
__global__ __launch_bounds__(256) void k_prep(
    const void* __restrict__ mask, int* __restrict__ lengths,
    const float* __restrict__ qs, const float* __restrict__ Wq,
    const float* __restrict__ Wk, float* __restrict__ wkq)
{
  const int blk = blockIdx.x, t = threadIdx.x;
  __shared__ float shb[800];
  if (blk < 32) {
    int* red = (int*)shb;
    const unsigned char* mb = (const unsigned char*)mask;
    int mode;
    if (mb[1] != 0) mode = 0;
    else if (((const int*)mask)[1] != 0) mode = 1;
    else mode = 2;
    int cnt = 0;
    for (int s = t; s < S_; s += 256) {
      int v;
      if (mode == 0)      v = mb[blk*S_ + s] ? 1 : 0;
      else if (mode == 1) v = ((const int*)mask)[blk*S_ + s] ? 1 : 0;
      else                v = ((const long long*)mask)[blk*S_ + s] ? 1 : 0;
      cnt += v;
    }
    red[t] = cnt;
    __syncthreads();
    for (int sft = 128; sft; sft >>= 1) {
      if (t < sft) red[t] += red[t+sft];
      __syncthreads();
    }
    if (t == 0) lengths[blk] = red[0];
  } else {
    float* qsl = shb;              // [400]
    float* qv  = shb + 400;        // [400]
    if (t < ENC_) qsl[t] = qs[t];
    if (t + 256 < ENC_) qsl[t+256] = qs[t+256];
    __syncthreads();
    {
      float acc = 0.f;
      for (int i = 0; i < ENC_; ++i) acc += qsl[i] * Wq[(size_t)i*ENC_ + t];
      qv[t] = acc;
      if (t + 256 < ENC_) {
        float acc2 = 0.f;
        for (int i = 0; i < ENC_; ++i) acc2 += qsl[i] * Wq[(size_t)i*ENC_ + t + 256];
        qv[t+256] = acc2;
      }
    }
    __syncthreads();
    const int e = (blk - 32)*64 + (t >> 2);
    const int head = t & 3;
    if (e < ENC_) {
      float acc = 0.f;
      const float* row = Wk + (size_t)e*ENC_ + head*100;
      const float* qvh = qv + head*100;
      for (int d = 0; d < 100; ++d) acc += row[d]*qvh[d];
      wkq[e*4 + head] = acc;
    }
  }
}

// -------- input projections via fp16 MFMA (builtins only; passing) --------
__global__ __launch_bounds__(256) void k_gemm_mfma(
    const int* __restrict__ x, const float* __restrict__ emb,
    const float* __restrict__ wf, const float* __restrict__ wb,
    const float* __restrict__ bf, const float* __restrict__ bb,
    float* __restrict__ xWf, float* __restrict__ xWb)
{
  __shared__ int xid[128];
  __shared__ __align__(16) _Float16 sA[128][40];
  __shared__ __align__(16) _Float16 sB[64][40];
  const int t = threadIdx.x;
  const int row0 = blockIdx.x * 128;
  const int col0 = blockIdx.y * 64;
  if (t < 128) xid[t] = x[row0 + t];
  const int w = t >> 6, lane = t & 63;
  const int wr = w >> 1, wc = w & 1;
  f32x4 acc[4][2] = {};
  const int ar = t >> 1, ah = t & 1;
  const int bc = t >> 2, bq = t & 3;
  const int colg = col0 + bc;
  const float* wsrc = (colg < 800) ? (wf + (size_t)colg*300)
                                   : (wb + (size_t)(colg-800)*300);
  __syncthreads();
  const float* asrc = emb + (size_t)xid[ar]*300;
  for (int kc = 0; kc < 10; ++kc) {
    const int k0 = kc*32;
    {
      const int kb = k0 + ah*16;
      _Float16 tmp[16];
      if (kb + 15 < 300) {
        #pragma unroll
        for (int q = 0; q < 4; ++q) {
          float4 a = *(const float4*)(asrc + kb + 4*q);
          tmp[4*q]  =(_Float16)a.x; tmp[4*q+1]=(_Float16)a.y;
          tmp[4*q+2]=(_Float16)a.z; tmp[4*q+3]=(_Float16)a.w;
        }
      } else {
        #pragma unroll
        for (int i = 0; i < 16; ++i)
          tmp[i] = (_Float16)((kb+i < 300) ? asrc[kb+i] : 0.f);
      }
      *(f16x8*)&sA[ar][ah*16]   = *(f16x8*)&tmp[0];
      *(f16x8*)&sA[ar][ah*16+8] = *(f16x8*)&tmp[8];
    }
    {
      const int kb = k0 + bq*8;
      _Float16 tmp[8];
      if (kb + 7 < 300) {
        #pragma unroll
        for (int q = 0; q < 2; ++q) {
          float4 a = *(const float4*)(wsrc + kb + 4*q);
          tmp[4*q]  =(_Float16)a.x; tmp[4*q+1]=(_Float16)a.y;
          tmp[4*q+2]=(_Float16)a.z; tmp[4*q+3]=(_Float16)a.w;
        }
      } else {
        #pragma unroll
        for (int i = 0; i < 8; ++i)
          tmp[i] = (_Float16)((kb+i < 300) ? wsrc[kb+i] : 0.f);
      }
      *(f16x8*)&sB[bc][bq*8] = *(f16x8*)&tmp[0];
    }
    __syncthreads();
    const int fr = lane & 15, kg = lane >> 4;
    f16x8 b0 = *(const f16x8*)&sB[wc*32 + fr][kg*8];
    f16x8 b1 = *(const f16x8*)&sB[wc*32 + 16 + fr][kg*8];
    #pragma unroll
    for (int m = 0; m < 4; ++m) {
      f16x8 afrag = *(const f16x8*)&sA[wr*64 + m*16 + fr][kg*8];
      acc[m][0] = __builtin_amdgcn_mfma_f32_16x16x32_f16(afrag, b0, acc[m][0], 0,0,0);
      acc[m][1] = __builtin_amdgcn_mfma_f32_16x16x32_f16(afrag, b1, acc[m][1], 0,0,0);
    }
    __syncthreads();
  }
  const int crb = (lane >> 4) * 4, ccol = lane & 15;
  #pragma unroll
  for (int n = 0; n < 2; ++n) {
    int colg2 = col0 + wc*32 + n*16 + ccol;
    bool isF = colg2 < 800;
    int colo = isF ? colg2 : colg2 - 800;
    float bias = isF ? bf[colo] : bb[colo];
    float* dst = isF ? xWf : xWb;
    #pragma unroll
    for (int m = 0; m < 4; ++m) {
      int row = row0 + wr*64 + m*16 + crb;
      #pragma unroll
      for (int r = 0; r < 4; ++r)
        dst[(size_t)(row+r)*800 + colo] = acc[m][n][r] + bias;
    }
  }
}

// -------- LSTM: k_lstm_ws — measured session-best (645 us), launched always --------
// 512 thr, __launch_bounds__(512,2): 128-VGPR grant, ~100 regs spilled to
// L1/L2-resident scratch. This is a two-pipe design the compiler arranges:
// LDS carries h-broadcast + sums (~600 cyc/step), the vector-L1 port carries
// spill refill (~1300+), VALU (~1000) hides beneath; measured 1.26 us/step.
// Placement alternatives measured and slower: all-LDS 925, split 814,
// 1024-thr AGPR-parked 678, (512,1) HBM-leak 3107. Numerics 5x validated.
__global__ __launch_bounds__(512, 2) void k_lstm_ws(
    const float* __restrict__ xWf, const float* __restrict__ xWb,
    const float* __restrict__ whhf, const float* __restrict__ whhb,
    const int* __restrict__ lengths,
    float* __restrict__ h_f, float* __restrict__ h_b)
{
  const int bid = blockIdx.x;
  const int dir = bid >> 5, b = bid & 31;
  const float* __restrict__ xW  = dir ? xWb : xWf;
  const float* __restrict__ whh = dir ? whhb : whhf;
  float* __restrict__ hout      = dir ? h_b : h_f;
  const int len = lengths[b];
  const int t = threadIdx.x;

  __shared__ __align__(16) _Float16 hb[256];
  __shared__ float sums[1024];

  half2v w0[100], w1[100];
  {
    const float* r0p = whh + (size_t)t*H_;
    #pragma unroll
    for (int j = 0; j < 50; ++j) {
      float4 a = *(const float4*)(r0p + 4*j);
      w0[2*j]   = half2v{(_Float16)a.x, (_Float16)a.y};
      w0[2*j+1] = half2v{(_Float16)a.z, (_Float16)a.w};
    }
    if (t < 288) {
      const float* r1p = whh + (size_t)(512+t)*H_;
      #pragma unroll
      for (int j = 0; j < 50; ++j) {
        float4 a = *(const float4*)(r1p + 4*j);
        w1[2*j]   = half2v{(_Float16)a.x, (_Float16)a.y};
        w1[2*j+1] = half2v{(_Float16)a.z, (_Float16)a.w};
      }
    } else {
      #pragma unroll
      for (int j = 0; j < 100; ++j) w1[j] = half2v{(_Float16)0.f, (_Float16)0.f};
    }
  }

  if (t < 256) hb[t] = (_Float16)0.f;
  float cst = 0.f;
  __syncthreads();

  for (int step = 0; step < len; ++step) {
    const int pos = dir ? (len-1-step) : step;
    float xi=0.f, xf=0.f, xg=0.f, xo=0.f;
    if (t < H_) {
      const float* xr = xW + ((size_t)b*S_ + pos)*G4_ + t;
      xi = xr[0]; xf = xr[H_]; xg = xr[2*H_]; xo = xr[3*H_];
    }
    float a0 = 0.f, a1 = 0.f;
    #pragma unroll
    for (int j = 0; j < 25; ++j) {
      float4 h4 = *(const float4*)&hb[8*j];
      half2v p0 = __builtin_bit_cast(half2v, h4.x);
      half2v p1 = __builtin_bit_cast(half2v, h4.y);
      half2v p2 = __builtin_bit_cast(half2v, h4.z);
      half2v p3 = __builtin_bit_cast(half2v, h4.w);
      a0 = FDOT2(w0[4*j],   p0, a0);
      a0 = FDOT2(w0[4*j+1], p1, a0);
      a0 = FDOT2(w0[4*j+2], p2, a0);
      a0 = FDOT2(w0[4*j+3], p3, a0);
      a1 = FDOT2(w1[4*j],   p0, a1);
      a1 = FDOT2(w1[4*j+1], p1, a1);
      a1 = FDOT2(w1[4*j+2], p2, a1);
      a1 = FDOT2(w1[4*j+3], p3, a1);
    }
    sums[t] = a0;
    sums[512+t] = a1;
    __syncthreads();
    if (t < H_) {
      float gi = sums[t]        + xi;
      float gf = sums[H_ + t]   + xf;
      float gg = sums[2*H_ + t] + xg;
      float go = sums[3*H_ + t] + xo;
      float ig = 1.f/(1.f+__expf(-gi));
      float fg = 1.f/(1.f+__expf(-gf));
      float og = 1.f/(1.f+__expf(-go));
      float ggc = fminf(fmaxf(gg, -10.f), 10.f);
      float eg = __expf(2.f*ggc);
      cst = fg*cst + ig*((eg-1.f)/(eg+1.f));
      float cc = fminf(fmaxf(cst, -10.f), 10.f);
      float ec = __expf(2.f*cc);
      float hn = og*((ec-1.f)/(ec+1.f));
      hout[((size_t)b*S_ + pos)*H_ + t] = hn;
      hb[t] = (_Float16)hn;
    }
    __syncthreads();
  }
}

// -------- scores --------
__global__ __launch_bounds__(256) void k_scores(
    const float* __restrict__ hf, const float* __restrict__ hb,
    const float* __restrict__ wkq, const int* __restrict__ lengths,
    float* __restrict__ theta)
{
  int wid = blockIdx.x*4 + (threadIdx.x >> 6);
  int lane = threadIdx.x & 63;
  int b = wid >> 9, s = wid & 511;
  const float* hfr = hf + ((size_t)b*S_ + s)*H_;
  const float* hbr = hb + ((size_t)b*S_ + s)*H_;
  bool valid = s < lengths[b];
  float a0=0.f, a1=0.f, a2=0.f, a3=0.f;
  if (valid) {
    for (int e = lane; e < ENC_; e += 64) {
      float hv = (e < H_) ? hfr[e] : hbr[e-H_];
      float4 w = *(const float4*)(wkq + e*4);
      a0 += hv*w.x; a1 += hv*w.y; a2 += hv*w.z; a3 += hv*w.w;
    }
    for (int off = 32; off; off >>= 1) {
      a0 += __shfl_xor(a0, off); a1 += __shfl_xor(a1, off);
      a2 += __shfl_xor(a2, off); a3 += __shfl_xor(a3, off);
    }
  }
  if (lane == 0) {
    size_t base = (size_t)b*2048 + s;
    theta[base       ] = valid ? SCALE_*a0 : NEGV;
    theta[base +  512] = valid ? SCALE_*a1 : NEGV;
    theta[base + 1024] = valid ? SCALE_*a2 : NEGV;
    theta[base + 1536] = valid ? SCALE_*a3 : NEGV;
  }
}

// -------- k_spzh: sparseMAP + z + hp + head fused, one block per b --------
__global__ __launch_bounds__(512) void k_spzh(
    const float* __restrict__ theta, const int* __restrict__ lengths,
    const float* __restrict__ hf, const float* __restrict__ hb,
    const float* __restrict__ Wv, const float* __restrict__ Wout,
    const float* __restrict__ Wh, const float* __restrict__ bh,
    float* __restrict__ out)
{
  const int b = blockIdx.x, t = threadIdx.x;
  __shared__ float muL[4][512];
  __shared__ float hpl[1600];
  __shared__ float ppl[ENC_];
  __shared__ float ojl[ENC_];
  __shared__ float red[512];
  const int len = lengths[b];

  if (t < 256) {
    const int head = t >> 6, lane = t & 63;
    const float* th = theta + ((size_t)b*4 + head)*512;
    float v[8];
    #pragma unroll
    for (int i = 0; i < 8; ++i) v[i] = th[i*64 + lane];
    float kf = rintf(0.2f * (float)len);
    float mn = v[0], mx = v[0];
    #pragma unroll
    for (int i = 1; i < 8; ++i) { mn = fminf(mn, v[i]); mx = fmaxf(mx, v[i]); }
    for (int off = 32; off; off >>= 1) {
      mn = fminf(mn, __shfl_xor(mn, off)); mx = fmaxf(mx, __shfl_xor(mx, off));
    }
    float lo = mn - 1.f, hi = mx;
    for (int it = 0; it < 60; ++it) {
      float mid = 0.5f*(lo + hi);
      float s = 0.f;
      #pragma unroll
      for (int i = 0; i < 8; ++i) s += fminf(fmaxf(v[i]-mid, 0.f), 1.f);
      for (int off = 32; off; off >>= 1) s += __shfl_xor(s, off);
      bool big = s > kf;
      lo = big ? mid : lo;
      hi = big ? hi : mid;
    }
    float tau0 = 0.5f*(lo + hi);
    float fs = 0.f, nU = 0.f, nS = 0.f;
    #pragma unroll
    for (int i = 0; i < 8; ++i) {
      float m0 = v[i] - tau0;
      if (m0 >= 1.f) nU += 1.f;
      else if (m0 > 0.f) { fs += v[i]; nS += 1.f; }
    }
    for (int off = 32; off; off >>= 1) {
      fs += __shfl_xor(fs, off); nU += __shfl_xor(nU, off); nS += __shfl_xor(nS, off);
    }
    float tau = (fs + nU - kf) / fmaxf(nS, 1.f);
    tau = (nS > 0.f) ? tau : tau0;
    #pragma unroll
    for (int i = 0; i < 8; ++i)
      muL[head][i*64 + lane] = fminf(fmaxf(v[i]-tau, 0.f), 1.f);
  }
  __syncthreads();

  {
    const int s = t;
    float zz = (s < len) ? 0.25f*(muL[0][s]+muL[1][s]+muL[2][s]+muL[3][s]) : 0.f;
    out[32 + b*S_ + s] = zz;
  }

  if (t < ENC_) {
    const float* hsrc = (t < H_) ? (hf + t) : (hb + (t - H_));
    float ac0 = 0.f, ac1 = 0.f, ac2 = 0.f, ac3 = 0.f;
    for (int s = 0; s < S_; ++s) {
      float hv = hsrc[((size_t)b*S_ + s)*H_];
      ac0 += muL[0][s]*hv; ac1 += muL[1][s]*hv;
      ac2 += muL[2][s]*hv; ac3 += muL[3][s]*hv;
    }
    hpl[t]        = ac0;
    hpl[400 + t]  = ac1;
    hpl[800 + t]  = ac2;
    hpl[1200 + t] = ac3;
  }
  __syncthreads();

  if (t < ENC_) {
    int head = t / 100;
    float acc = 0.f;
    for (int e = 0; e < ENC_; ++e) acc += hpl[head*ENC_ + e] * Wv[(size_t)e*ENC_ + t];
    ppl[t] = acc;
  }
  __syncthreads();
  if (t < ENC_) {
    float acc = 0.f;
    for (int c = 0; c < ENC_; ++c) acc += ppl[c] * Wout[(size_t)c*ENC_ + t];
    ojl[t] = acc;
  }
  __syncthreads();
  red[t] = (t < ENC_) ? ojl[t]*Wh[t] : 0.f;
  __syncthreads();
  for (int sft = 256; sft; sft >>= 1) {
    if (t < sft) red[t] += red[t+sft];
    __syncthreads();
  }
  if (t == 0) out[b] = 1.f/(1.f + expf(-(red[0] + bh[0])));
}

extern "C" void kernel_launch(void* const* d_in, const int* in_sizes, int n_in,
                              void* d_out, int out_size, void* d_ws, size_t ws_size,
                              hipStream_t stream) {
  const int*   x    = (const int*)d_in[0];
  const void*  mask = d_in[1];
  const float* emb  = (const float*)d_in[2];
  const float* wihf = (const float*)d_in[3];
  const float* whhf = (const float*)d_in[4];
  const float* bf   = (const float*)d_in[5];
  const float* wihb = (const float*)d_in[6];
  const float* whhb = (const float*)d_in[7];
  const float* bb   = (const float*)d_in[8];
  const float* qs   = (const float*)d_in[9];
  const float* Wq   = (const float*)d_in[10];
  const float* Wk   = (const float*)d_in[11];
  const float* Wv   = (const float*)d_in[12];
  const float* Wout = (const float*)d_in[13];
  const float* Wh   = (const float*)d_in[14];
  const float* bh   = (const float*)d_in[15];
  float* out = (float*)d_out;
  float* W = (float*)d_ws;
  int* lengths = (int*)(W + OF_LEN);

  k_prep<<<39, 256, 0, stream>>>(mask, lengths, qs, Wq, Wk, W+OF_WKQ);
  k_gemm_mfma<<<dim3(128, 25), 256, 0, stream>>>(x, emb, wihf, wihb, bf, bb,
                                                 W+OF_XWF, W+OF_XWB);
  k_lstm_ws<<<64, 512, 0, stream>>>(W+OF_XWF, W+OF_XWB, whhf, whhb,
                                    lengths, W+OF_HF, W+OF_HB);
  k_scores<<<4096, 256, 0, stream>>>(W+OF_HF, W+OF_HB, W+OF_WKQ, lengths, W+OF_THETA);
  k_spzh<<<32, 512, 0, stream>>>(W+OF_THETA, lengths, W+OF_HF, W+OF_HB,
                                 Wv, Wout, Wh, bh, out);
}